// Round 4
// baseline (131.536 us; speedup 1.0000x reference)
//
#include <hip/hip_runtime.h>

#define GAMMA 0.99f
#define TAU   0.95f

constexpr int SEQ   = 16;          // elements per thread
constexpr int BLK   = 256;         // threads per block
constexpr int CHUNK = BLK * SEQ;   // 4096 elements per block

// (A,B) = (A,B) ∘ (rA,rB)  — apply right operand first, then (A,B)
__device__ __forceinline__ void post_compose(float& A, float& B, float rA, float rB) {
    B = fmaf(A, rB, B);
    A *= rA;
}
// (A,B) = (lA,lB) ∘ (A,B)  — apply (A,B) first, then left operand
__device__ __forceinline__ void pre_compose(float& A, float& B, float lA, float lB) {
    B = fmaf(lA, B, lB);
    A *= lA;
}

// =====================================================================
// Single-pass suffix scan with decoupled lookback on aggregates.
// Block b processes chunk c = nblk-1-b, so every chunk it depends on
// (c+1 .. nblk-1) belongs to an EARLIER-dispatched block index -> with
// in-order workgroup dispatch no block ever waits on a later block
// (deadlock-free at any residency). Requires nblk <= 1024.
// =====================================================================
__global__ __launch_bounds__(BLK) void k_onepass(
    const float* __restrict__ r, const float* __restrict__ v,
    const float* __restrict__ nv, const int* __restrict__ m,
    int* __restrict__ flag, float4* __restrict__ Sarr,
    float* __restrict__ out_adv, float* __restrict__ out_ret, int T, int nblk)
{
    const int  tid  = threadIdx.x;
    const int  lane = tid & 63;
    const int  w    = tid >> 6;
    const int  c    = nblk - 1 - (int)blockIdx.x;   // chunk index (reversed)
    const long base = (long)c * CHUNK + (long)tid * SEQ;

    __shared__ float  wSum[4][4];
    __shared__ float  s_cb[2];
    __shared__ float4 sS[1024];

    // ---------------- Phase A: load chunk + per-element maps ----------------
    float fm[SEQ], delta[SEQ], dd[SEQ];
    unsigned vbits = 0;
    float Aa = 1.f, Ba = 0.f, Ar = 1.f, Br = 0.f;
    const bool full = (base + SEQ <= (long)T);

    if (full) {
        vbits = 0xFFFFu;
        float rr[SEQ], vv[SEQ + 1], nn[SEQ];
        #pragma unroll
        for (int q = 0; q < SEQ / 4; ++q) {
            float4 t0 = ((const float4*)(r  + base))[q];
            rr[4*q+0]=t0.x; rr[4*q+1]=t0.y; rr[4*q+2]=t0.z; rr[4*q+3]=t0.w;
            float4 t1 = ((const float4*)(v  + base))[q];
            vv[4*q+0]=t1.x; vv[4*q+1]=t1.y; vv[4*q+2]=t1.z; vv[4*q+3]=t1.w;
            float4 t2 = ((const float4*)(nv + base))[q];
            nn[4*q+0]=t2.x; nn[4*q+1]=t2.y; nn[4*q+2]=t2.z; nn[4*q+3]=t2.w;
            int4   t3 = ((const int4*)(m   + base))[q];
            fm[4*q+0]=(float)t3.x; fm[4*q+1]=(float)t3.y;
            fm[4*q+2]=(float)t3.z; fm[4*q+3]=(float)t3.w;
        }
        vv[SEQ] = (base + SEQ < (long)T) ? v[base + SEQ] : 0.f;
        #pragma unroll
        for (int i = SEQ - 1; i >= 0; --i) {
            delta[i] = rr[i] + GAMMA * fm[i] * vv[i+1] - vv[i];
            dd[i]    = rr[i] + GAMMA * (1.f - fm[i]) * nn[i];
            pre_compose(Aa, Ba, GAMMA * TAU * fm[i], delta[i]);
            pre_compose(Ar, Br, GAMMA * fm[i], dd[i]);
        }
    } else {
        #pragma unroll
        for (int ii = 0; ii < SEQ; ++ii) {
            int i = SEQ - 1 - ii;
            long idx = base + i;
            bool val = idx < (long)T;
            float rr  = val ? r[idx]  : 0.f;
            float vv0 = val ? v[idx]  : 0.f;
            float vv1 = (idx + 1 < (long)T) ? v[idx + 1] : 0.f;
            float nn  = val ? nv[idx] : 0.f;
            fm[i] = val ? (float)m[idx] : 0.f;
            if (val) vbits |= (1u << i);
            delta[i] = val ? (rr + GAMMA * fm[i] * vv1 - vv0) : 0.f;
            dd[i]    = val ? (rr + GAMMA * (1.f - fm[i]) * nn) : 0.f;
            pre_compose(Aa, Ba, val ? GAMMA * TAU * fm[i] : 1.f, delta[i]);
            pre_compose(Ar, Br, val ? GAMMA * fm[i] : 1.f, dd[i]);
        }
    }

    // wave-level inclusive suffix scan (contiguous segments, non-commutative OK)
    #pragma unroll
    for (int st = 1; st < 64; st <<= 1) {
        float oAa = __shfl_down(Aa, st);
        float oBa = __shfl_down(Ba, st);
        float oAr = __shfl_down(Ar, st);
        float oBr = __shfl_down(Br, st);
        if (lane + st < 64) {
            post_compose(Aa, Ba, oAa, oBa);
            post_compose(Ar, Br, oAr, oBr);
        }
    }
    // thread-exclusive (within wave)
    float eAa = __shfl_down(Aa, 1);
    float eBa = __shfl_down(Ba, 1);
    float eAr = __shfl_down(Ar, 1);
    float eBr = __shfl_down(Br, 1);
    if (lane == 63) { eAa=1.f; eBa=0.f; eAr=1.f; eBr=0.f; }

    if (lane == 0) { wSum[w][0]=Aa; wSum[w][1]=Ba; wSum[w][2]=Ar; wSum[w][3]=Br; }
    __syncthreads();                                   // S1: wSum ready

    // per-thread wave-exclusive map (waves w+1..3), kept in registers
    float WAa=1.f, WBa=0.f, WAr=1.f, WBr=0.f;
    for (int j = 3; j > w; --j) {
        pre_compose(WAa, WBa, wSum[j][0], wSum[j][1]);
        pre_compose(WAr, WBr, wSum[j][2], wSum[j][3]);
    }

    // tid0: publish this block's aggregate
    if (tid == 0) {
        float SAa=1.f, SBa=0.f, SAr=1.f, SBr=0.f;
        for (int j = 3; j >= 0; --j) {
            pre_compose(SAa, SBa, wSum[j][0], wSum[j][1]);
            pre_compose(SAr, SBr, wSum[j][2], wSum[j][3]);
        }
        Sarr[c] = make_float4(SAa, SBa, SAr, SBr);
        __hip_atomic_store(&flag[c], 1, __ATOMIC_RELEASE, __HIP_MEMORY_SCOPE_AGENT);
        s_cb[0] = 0.f; s_cb[1] = 0.f;
    }

    // wave 0: gather all summaries into LDS, waiting only on chunks > c.
    // Chunks <= c get the identity map — they provably cannot affect the
    // value extracted at position p = c+1 (they fold only into positions < p).
    if (w == 0) {
        #pragma unroll
        for (int g = 0; g < 16; ++g) {
            int idx = g * 64 + lane;                   // 0..1023
            if (idx > c && idx < nblk) {
                while (__hip_atomic_load(&flag[idx], __ATOMIC_ACQUIRE,
                                         __HIP_MEMORY_SCOPE_AGENT) == 0) {
                    __builtin_amdgcn_s_sleep(2);
                }
                sS[idx] = Sarr[idx];
            } else {
                sS[idx] = make_float4(1.f, 0.f, 1.f, 0.f);
            }
        }
    }
    __syncthreads();                                   // S2: sS ready

    // ---------------- Phase B: redundant scan of summaries (from LDS) ----------------
    const int p = c + 1;
    float sA[4][4];
    float gAa=1.f, gBa=0.f, gAr=1.f, gBr=0.f;
    #pragma unroll
    for (int j = 3; j >= 0; --j) {
        float4 s = sS[4 * tid + j];
        sA[j][0]=s.x; sA[j][1]=s.y; sA[j][2]=s.z; sA[j][3]=s.w;
        pre_compose(gAa, gBa, s.x, s.y);
        pre_compose(gAr, gBr, s.z, s.w);
    }
    #pragma unroll
    for (int st = 1; st < 64; st <<= 1) {
        float oAa = __shfl_down(gAa, st);
        float oBa = __shfl_down(gBa, st);
        float oAr = __shfl_down(gAr, st);
        float oBr = __shfl_down(gBr, st);
        if (lane + st < 64) {
            post_compose(gAa, gBa, oAa, oBa);
            post_compose(gAr, gBr, oAr, oBr);
        }
    }
    float e2Aa = __shfl_down(gAa, 1);
    float e2Ba = __shfl_down(gBa, 1);
    float e2Ar = __shfl_down(gAr, 1);
    float e2Br = __shfl_down(gBr, 1);
    if (lane == 63) { e2Aa=1.f; e2Ba=0.f; e2Ar=1.f; e2Br=0.f; }

    if (lane == 0) { wSum[w][0]=gAa; wSum[w][1]=gBa; wSum[w][2]=gAr; wSum[w][3]=gBr; }
    __syncthreads();                                   // S3: summary wave sums ready

    float XAa=1.f, XBa=0.f, XAr=1.f, XBr=0.f;
    for (int j = 3; j > w; --j) {
        pre_compose(XAa, XBa, wSum[j][0], wSum[j][1]);
        pre_compose(XAr, XBr, wSum[j][2], wSum[j][3]);
    }
    post_compose(e2Aa, e2Ba, XAa, XBa);
    post_compose(e2Ar, e2Br, XAr, XBr);

    float valA = e2Ba, valR = e2Br;
    #pragma unroll
    for (int j = 3; j >= 0; --j) {
        valA = fmaf(sA[j][0], valA, sA[j][1]);
        valR = fmaf(sA[j][2], valR, sA[j][3]);
        if (4 * tid + j == p) { s_cb[0] = valA; s_cb[1] = valR; }
    }
    __syncthreads();                                   // S4: carry ready
    const float cbA = s_cb[0];
    const float cbR = s_cb[1];

    // ---------------- Phase C: replay + store ----------------
    float xa = fmaf(WAa, cbA, WBa);   // value at this wave's right edge
    float xr = fmaf(WAr, cbR, WBr);
    xa = fmaf(eAa, xa, eBa);          // value at this thread's right edge
    xr = fmaf(eAr, xr, eBr);

    float ra[SEQ], rt[SEQ];
    #pragma unroll
    for (int i = SEQ - 1; i >= 0; --i) {
        bool val = (vbits >> i) & 1u;
        float a = val ? GAMMA * TAU * fm[i] : 1.f;
        float cc = val ? GAMMA * fm[i]      : 1.f;
        xa = fmaf(a, xa, delta[i]);
        xr = fmaf(cc, xr, dd[i]);
        ra[i] = xa; rt[i] = xr;
    }

    if (full) {
        #pragma unroll
        for (int q = 0; q < SEQ / 4; ++q) {
            ((float4*)(out_adv + base))[q] =
                make_float4(ra[4*q], ra[4*q+1], ra[4*q+2], ra[4*q+3]);
            ((float4*)(out_ret + base))[q] =
                make_float4(rt[4*q], rt[4*q+1], rt[4*q+2], rt[4*q+3]);
        }
    } else {
        #pragma unroll
        for (int i = 0; i < SEQ; ++i) {
            if (base + i < (long)T) {
                out_adv[base + i] = ra[i];
                out_ret[base + i] = rt[i];
            }
        }
    }
}

// =====================================================================
// Fallback 3-kernel path (verified round 1) — used only if nblk > 1024.
// =====================================================================
__global__ __launch_bounds__(BLK) void k_summary(
    const float* __restrict__ r, const float* __restrict__ v,
    const float* __restrict__ nv, const int* __restrict__ m,
    float4* __restrict__ blk_sum, int T)
{
    const int  tid  = threadIdx.x;
    const int  lane = tid & 63;
    const int  w    = tid >> 6;
    const long base = (long)blockIdx.x * CHUNK + (long)tid * SEQ;

    float Aa = 1.f, Ba = 0.f, Ar = 1.f, Br = 0.f;

    if (base + SEQ <= (long)T) {
        float rr[SEQ], vv[SEQ + 1], nn[SEQ], fm[SEQ];
        #pragma unroll
        for (int q = 0; q < SEQ / 4; ++q) {
            float4 t0 = ((const float4*)(r  + base))[q];
            rr[4*q+0]=t0.x; rr[4*q+1]=t0.y; rr[4*q+2]=t0.z; rr[4*q+3]=t0.w;
            float4 t1 = ((const float4*)(v  + base))[q];
            vv[4*q+0]=t1.x; vv[4*q+1]=t1.y; vv[4*q+2]=t1.z; vv[4*q+3]=t1.w;
            float4 t2 = ((const float4*)(nv + base))[q];
            nn[4*q+0]=t2.x; nn[4*q+1]=t2.y; nn[4*q+2]=t2.z; nn[4*q+3]=t2.w;
            int4   t3 = ((const int4*)(m   + base))[q];
            fm[4*q+0]=(float)t3.x; fm[4*q+1]=(float)t3.y;
            fm[4*q+2]=(float)t3.z; fm[4*q+3]=(float)t3.w;
        }
        vv[SEQ] = (base + SEQ < (long)T) ? v[base + SEQ] : 0.f;
        #pragma unroll
        for (int i = SEQ - 1; i >= 0; --i) {
            pre_compose(Aa, Ba, GAMMA * TAU * fm[i], rr[i] + GAMMA * fm[i] * vv[i+1] - vv[i]);
            pre_compose(Ar, Br, GAMMA * fm[i], rr[i] + GAMMA * (1.f - fm[i]) * nn[i]);
        }
    } else if (base < (long)T) {
        #pragma unroll
        for (int ii = 0; ii < SEQ; ++ii) {
            int i = SEQ - 1 - ii;
            long idx = base + i;
            bool val = idx < (long)T;
            float rr  = val ? r[idx]  : 0.f;
            float vv0 = val ? v[idx]  : 0.f;
            float vv1 = (idx + 1 < (long)T) ? v[idx + 1] : 0.f;
            float nn  = val ? nv[idx] : 0.f;
            float fmv = val ? (float)m[idx] : 0.f;
            pre_compose(Aa, Ba, val ? GAMMA * TAU * fmv : 1.f,
                        val ? (rr + GAMMA * fmv * vv1 - vv0) : 0.f);
            pre_compose(Ar, Br, val ? GAMMA * fmv : 1.f,
                        val ? (rr + GAMMA * (1.f - fmv) * nn) : 0.f);
        }
    }

    #pragma unroll
    for (int st = 1; st < 64; st <<= 1) {
        float oAa = __shfl_down(Aa, st);
        float oBa = __shfl_down(Ba, st);
        float oAr = __shfl_down(Ar, st);
        float oBr = __shfl_down(Br, st);
        if (lane + st < 64) {
            post_compose(Aa, Ba, oAa, oBa);
            post_compose(Ar, Br, oAr, oBr);
        }
    }

    __shared__ float wSum[4][4];
    if (lane == 0) { wSum[w][0]=Aa; wSum[w][1]=Ba; wSum[w][2]=Ar; wSum[w][3]=Br; }
    __syncthreads();
    if (tid == 0) {
        float SAa=1.f, SBa=0.f, SAr=1.f, SBr=0.f;
        for (int j = 3; j >= 0; --j) {
            pre_compose(SAa, SBa, wSum[j][0], wSum[j][1]);
            pre_compose(SAr, SBr, wSum[j][2], wSum[j][3]);
        }
        blk_sum[blockIdx.x] = make_float4(SAa, SBa, SAr, SBr);
    }
}

__global__ __launch_bounds__(1024) void k_scan(
    const float4* __restrict__ blk_sum, float2* __restrict__ carry, int n)
{
    __shared__ float sAa[1024], sBa[1024], sAr[1024], sBr[1024];
    const int t = threadIdx.x;
    float Aa=1.f, Ba=0.f, Ar=1.f, Br=0.f;
    if (t < n) { float4 s = blk_sum[t]; Aa=s.x; Ba=s.y; Ar=s.z; Br=s.w; }
    sAa[t]=Aa; sBa[t]=Ba; sAr[t]=Ar; sBr[t]=Br;
    __syncthreads();
    for (int st = 1; st < 1024; st <<= 1) {
        float oAa=1.f, oBa=0.f, oAr=1.f, oBr=0.f;
        if (t + st < 1024) { oAa=sAa[t+st]; oBa=sBa[t+st]; oAr=sAr[t+st]; oBr=sBr[t+st]; }
        __syncthreads();
        post_compose(Aa, Ba, oAa, oBa);
        post_compose(Ar, Br, oAr, oBr);
        sAa[t]=Aa; sBa[t]=Ba; sAr[t]=Ar; sBr[t]=Br;
        __syncthreads();
    }
    if (t < n) {
        float ca = (t + 1 < n) ? sBa[t+1] : 0.f;
        float cr = (t + 1 < n) ? sBr[t+1] : 0.f;
        carry[t] = make_float2(ca, cr);
    }
}

__global__ __launch_bounds__(BLK) void k_final(
    const float* __restrict__ r, const float* __restrict__ v,
    const float* __restrict__ nv, const int* __restrict__ m,
    const float2* __restrict__ carry,
    float* __restrict__ out_adv, float* __restrict__ out_ret, int T)
{
    const int  tid  = threadIdx.x;
    const int  lane = tid & 63;
    const int  w    = tid >> 6;
    const long base = (long)blockIdx.x * CHUNK + (long)tid * SEQ;

    float delta[SEQ], dd[SEQ], fm[SEQ];
    unsigned vbits = 0;
    float Aa = 1.f, Ba = 0.f, Ar = 1.f, Br = 0.f;
    const bool full = (base + SEQ <= (long)T);

    if (full) {
        vbits = 0xFFFFu;
        float rr[SEQ], vv[SEQ + 1], nn[SEQ];
        #pragma unroll
        for (int q = 0; q < SEQ / 4; ++q) {
            float4 t0 = ((const float4*)(r  + base))[q];
            rr[4*q+0]=t0.x; rr[4*q+1]=t0.y; rr[4*q+2]=t0.z; rr[4*q+3]=t0.w;
            float4 t1 = ((const float4*)(v  + base))[q];
            vv[4*q+0]=t1.x; vv[4*q+1]=t1.y; vv[4*q+2]=t1.z; vv[4*q+3]=t1.w;
            float4 t2 = ((const float4*)(nv + base))[q];
            nn[4*q+0]=t2.x; nn[4*q+1]=t2.y; nn[4*q+2]=t2.z; nn[4*q+3]=t2.w;
            int4   t3 = ((const int4*)(m   + base))[q];
            fm[4*q+0]=(float)t3.x; fm[4*q+1]=(float)t3.y;
            fm[4*q+2]=(float)t3.z; fm[4*q+3]=(float)t3.w;
        }
        vv[SEQ] = (base + SEQ < (long)T) ? v[base + SEQ] : 0.f;
        #pragma unroll
        for (int i = SEQ - 1; i >= 0; --i) {
            delta[i] = rr[i] + GAMMA * fm[i] * vv[i+1] - vv[i];
            dd[i]    = rr[i] + GAMMA * (1.f - fm[i]) * nn[i];
            pre_compose(Aa, Ba, GAMMA * TAU * fm[i], delta[i]);
            pre_compose(Ar, Br, GAMMA * fm[i], dd[i]);
        }
    } else {
        #pragma unroll
        for (int ii = 0; ii < SEQ; ++ii) {
            int i = SEQ - 1 - ii;
            long idx = base + i;
            bool val = idx < (long)T;
            float rr  = val ? r[idx]  : 0.f;
            float vv0 = val ? v[idx]  : 0.f;
            float vv1 = (idx + 1 < (long)T) ? v[idx + 1] : 0.f;
            float nn  = val ? nv[idx] : 0.f;
            fm[i] = val ? (float)m[idx] : 0.f;
            if (val) vbits |= (1u << i);
            delta[i] = val ? (rr + GAMMA * fm[i] * vv1 - vv0) : 0.f;
            dd[i]    = val ? (rr + GAMMA * (1.f - fm[i]) * nn) : 0.f;
            pre_compose(Aa, Ba, val ? GAMMA * TAU * fm[i] : 1.f, delta[i]);
            pre_compose(Ar, Br, val ? GAMMA * fm[i] : 1.f, dd[i]);
        }
    }

    #pragma unroll
    for (int st = 1; st < 64; st <<= 1) {
        float oAa = __shfl_down(Aa, st);
        float oBa = __shfl_down(Ba, st);
        float oAr = __shfl_down(Ar, st);
        float oBr = __shfl_down(Br, st);
        if (lane + st < 64) {
            post_compose(Aa, Ba, oAa, oBa);
            post_compose(Ar, Br, oAr, oBr);
        }
    }
    float eAa = __shfl_down(Aa, 1);
    float eBa = __shfl_down(Ba, 1);
    float eAr = __shfl_down(Ar, 1);
    float eBr = __shfl_down(Br, 1);
    if (lane == 63) { eAa=1.f; eBa=0.f; eAr=1.f; eBr=0.f; }

    __shared__ float wSum[4][4];
    if (lane == 0) { wSum[w][0]=Aa; wSum[w][1]=Ba; wSum[w][2]=Ar; wSum[w][3]=Br; }
    __syncthreads();

    float WAa=1.f, WBa=0.f, WAr=1.f, WBr=0.f;
    for (int j = 3; j > w; --j) {
        pre_compose(WAa, WBa, wSum[j][0], wSum[j][1]);
        pre_compose(WAr, WBr, wSum[j][2], wSum[j][3]);
    }

    float2 cb = carry[blockIdx.x];
    float xa = fmaf(WAa, cb.x, WBa);
    float xr = fmaf(WAr, cb.y, WBr);
    xa = fmaf(eAa, xa, eBa);
    xr = fmaf(eAr, xr, eBr);

    float ra[SEQ], rt[SEQ];
    #pragma unroll
    for (int i = SEQ - 1; i >= 0; --i) {
        bool val = (vbits >> i) & 1u;
        float a = val ? GAMMA * TAU * fm[i] : 1.f;
        float cc = val ? GAMMA * fm[i]      : 1.f;
        xa = fmaf(a, xa, delta[i]);
        xr = fmaf(cc, xr, dd[i]);
        ra[i] = xa; rt[i] = xr;
    }

    if (full) {
        #pragma unroll
        for (int q = 0; q < SEQ / 4; ++q) {
            ((float4*)(out_adv + base))[q] =
                make_float4(ra[4*q], ra[4*q+1], ra[4*q+2], ra[4*q+3]);
            ((float4*)(out_ret + base))[q] =
                make_float4(rt[4*q], rt[4*q+1], rt[4*q+2], rt[4*q+3]);
        }
    } else {
        #pragma unroll
        for (int i = 0; i < SEQ; ++i) {
            if (base + i < (long)T) {
                out_adv[base + i] = ra[i];
                out_ret[base + i] = rt[i];
            }
        }
    }
}

extern "C" void kernel_launch(void* const* d_in, const int* in_sizes, int n_in,
                              void* d_out, int out_size, void* d_ws, size_t ws_size,
                              hipStream_t stream) {
    const float* r  = (const float*)d_in[0];
    const float* v  = (const float*)d_in[1];
    const float* nv = (const float*)d_in[2];
    const int*   m  = (const int*)d_in[3];
    const int T = in_sizes[0];
    const int nblk = (T + CHUNK - 1) / CHUNK;   // 1024 for T = 4'194'304

    // ws layout: [ flags: nblk ints ][ Sarr: nblk float4 ][ carry: nblk float2 ]
    int*    flag    = (int*)d_ws;
    size_t  off     = ((size_t)nblk * sizeof(int) + 15) & ~(size_t)15;
    float4* Sarr    = (float4*)((char*)d_ws + off);
    float2* carry   = (float2*)((char*)Sarr + (size_t)nblk * sizeof(float4));

    float* out_adv = (float*)d_out;
    float* out_ret = (float*)d_out + T;

    if (nblk <= 1024) {
        hipMemsetAsync(flag, 0, (size_t)nblk * sizeof(int), stream);
        k_onepass<<<nblk, BLK, 0, stream>>>(r, v, nv, m, flag, Sarr,
                                            out_adv, out_ret, T, nblk);
    } else {
        k_summary<<<nblk, BLK, 0, stream>>>(r, v, nv, m, Sarr, T);
        k_scan<<<1, 1024, 0, stream>>>(Sarr, carry, nblk);
        k_final<<<nblk, BLK, 0, stream>>>(r, v, nv, m, carry, out_adv, out_ret, T);
    }
}

// Round 6
// 127.090 us; speedup vs baseline: 1.0350x; 1.0350x over previous
//
#include <hip/hip_runtime.h>

#define GAMMA 0.99f
#define TAU   0.95f

constexpr int SEQ   = 16;          // elements per thread
constexpr int BLK   = 256;         // threads per block
constexpr int CHUNK = BLK * SEQ;   // 4096 elements per block

// (A,B) = (A,B) ∘ (rA,rB)  — apply right operand first, then (A,B)
__device__ __forceinline__ void post_compose(float& A, float& B, float rA, float rB) {
    B = fmaf(A, rB, B);
    A *= rA;
}
// (A,B) = (lA,lB) ∘ (A,B)  — apply (A,B) first, then left operand
__device__ __forceinline__ void pre_compose(float& A, float& B, float lA, float lB) {
    B = fmaf(lA, B, lB);
    A *= lA;
}

// =====================================================================
// Single-pass suffix scan, CUB-style decoupled lookback.
// Block b processes chunk c = nblk-1-b (reversed), so every chunk it
// depends on (c+1 .. nblk-1) belongs to an EARLIER-dispatched block ->
// with in-order workgroup dispatch no block waits on a later block.
// flag[j]: 0 = nothing, 1 = aggregate in Sarr[j], 2 = inclusive in Incl[j].
// Lookback walks predecessors in 64-wide batches; stops at first flag==2.
// =====================================================================
__global__ __launch_bounds__(BLK) void k_onepass(
    const float* __restrict__ r, const float* __restrict__ v,
    const float* __restrict__ nv, const int* __restrict__ m,
    int* __restrict__ flag, float4* __restrict__ Sarr, float4* __restrict__ Incl,
    float* __restrict__ out_adv, float* __restrict__ out_ret, int T, int nblk)
{
    const int  tid  = threadIdx.x;
    const int  lane = tid & 63;
    const int  w    = tid >> 6;
    const int  c    = nblk - 1 - (int)blockIdx.x;   // chunk index (reversed)
    const long base = (long)c * CHUNK + (long)tid * SEQ;

    __shared__ float wSum[4][4];
    __shared__ float s_cb[2];

    // ---------------- Phase A: load chunk + per-element maps ----------------
    float fm[SEQ], delta[SEQ], dd[SEQ];
    unsigned vbits = 0;
    float Aa = 1.f, Ba = 0.f, Ar = 1.f, Br = 0.f;
    const bool full = (base + SEQ <= (long)T);

    if (full) {
        vbits = 0xFFFFu;
        float rr[SEQ], vv[SEQ + 1], nn[SEQ];
        #pragma unroll
        for (int q = 0; q < SEQ / 4; ++q) {
            float4 t0 = ((const float4*)(r  + base))[q];
            rr[4*q+0]=t0.x; rr[4*q+1]=t0.y; rr[4*q+2]=t0.z; rr[4*q+3]=t0.w;
            float4 t1 = ((const float4*)(v  + base))[q];
            vv[4*q+0]=t1.x; vv[4*q+1]=t1.y; vv[4*q+2]=t1.z; vv[4*q+3]=t1.w;
            float4 t2 = ((const float4*)(nv + base))[q];
            nn[4*q+0]=t2.x; nn[4*q+1]=t2.y; nn[4*q+2]=t2.z; nn[4*q+3]=t2.w;
            int4   t3 = ((const int4*)(m   + base))[q];
            fm[4*q+0]=(float)t3.x; fm[4*q+1]=(float)t3.y;
            fm[4*q+2]=(float)t3.z; fm[4*q+3]=(float)t3.w;
        }
        vv[SEQ] = (base + SEQ < (long)T) ? v[base + SEQ] : 0.f;
        #pragma unroll
        for (int i = SEQ - 1; i >= 0; --i) {
            delta[i] = rr[i] + GAMMA * fm[i] * vv[i+1] - vv[i];
            dd[i]    = rr[i] + GAMMA * (1.f - fm[i]) * nn[i];
            pre_compose(Aa, Ba, GAMMA * TAU * fm[i], delta[i]);
            pre_compose(Ar, Br, GAMMA * fm[i], dd[i]);
        }
    } else {
        #pragma unroll
        for (int ii = 0; ii < SEQ; ++ii) {
            int i = SEQ - 1 - ii;
            long idx = base + i;
            bool val = idx < (long)T;
            float rr  = val ? r[idx]  : 0.f;
            float vv0 = val ? v[idx]  : 0.f;
            float vv1 = (idx + 1 < (long)T) ? v[idx + 1] : 0.f;
            float nn  = val ? nv[idx] : 0.f;
            fm[i] = val ? (float)m[idx] : 0.f;
            if (val) vbits |= (1u << i);
            delta[i] = val ? (rr + GAMMA * fm[i] * vv1 - vv0) : 0.f;
            dd[i]    = val ? (rr + GAMMA * (1.f - fm[i]) * nn) : 0.f;
            pre_compose(Aa, Ba, val ? GAMMA * TAU * fm[i] : 1.f, delta[i]);
            pre_compose(Ar, Br, val ? GAMMA * fm[i] : 1.f, dd[i]);
        }
    }

    // wave-level inclusive suffix scan (contiguous segments, non-commutative OK)
    #pragma unroll
    for (int st = 1; st < 64; st <<= 1) {
        float oAa = __shfl_down(Aa, st);
        float oBa = __shfl_down(Ba, st);
        float oAr = __shfl_down(Ar, st);
        float oBr = __shfl_down(Br, st);
        if (lane + st < 64) {
            post_compose(Aa, Ba, oAa, oBa);
            post_compose(Ar, Br, oAr, oBr);
        }
    }
    // thread-exclusive (within wave)
    float eAa = __shfl_down(Aa, 1);
    float eBa = __shfl_down(Ba, 1);
    float eAr = __shfl_down(Ar, 1);
    float eBr = __shfl_down(Br, 1);
    if (lane == 63) { eAa=1.f; eBa=0.f; eAr=1.f; eBr=0.f; }

    if (lane == 0) { wSum[w][0]=Aa; wSum[w][1]=Ba; wSum[w][2]=Ar; wSum[w][3]=Br; }
    __syncthreads();                                   // S1: wSum ready

    // per-thread wave-exclusive map (waves w+1..3), kept in registers
    float WAa=1.f, WBa=0.f, WAr=1.f, WBr=0.f;
    for (int j = 3; j > w; --j) {
        pre_compose(WAa, WBa, wSum[j][0], wSum[j][1]);
        pre_compose(WAr, WBr, wSum[j][2], wSum[j][3]);
    }

    // tid0: block aggregate S_c -> publish (flag=1, release)
    float SAa=1.f, SBa=0.f, SAr=1.f, SBr=0.f;
    if (tid == 0) {
        for (int j = 3; j >= 0; --j) {
            pre_compose(SAa, SBa, wSum[j][0], wSum[j][1]);
            pre_compose(SAr, SBr, wSum[j][2], wSum[j][3]);
        }
        Sarr[c] = make_float4(SAa, SBa, SAr, SBr);
        __hip_atomic_store(&flag[c], 1, __ATOMIC_RELEASE, __HIP_MEMORY_SCOPE_AGENT);
    }

    // ---------------- Lookback (wave 0): M = S_{c+1} ∘ ... ∘ Incl_j ----------------
    if (w == 0) {
        float MAa=1.f, MBa=0.f, MAr=1.f, MBr=0.f;
        int jbase = c + 1;
        while (jbase < nblk) {
            int j = jbase + lane;
            int f = 2;                                  // beyond-end = inclusive identity
            if (j < nblk) {
                // acquire spin: orders the Sarr/Incl reads below after the flag
                f = __hip_atomic_load(&flag[j], __ATOMIC_ACQUIRE, __HIP_MEMORY_SCOPE_AGENT);
                while (f == 0) {
                    __builtin_amdgcn_s_sleep(4);
                    f = __hip_atomic_load(&flag[j], __ATOMIC_ACQUIRE, __HIP_MEMORY_SCOPE_AGENT);
                }
            }

            unsigned long long mask2 = __ballot(f == 2);
            int L = (mask2 == 0) ? 64 : (__ffsll((long long)mask2) - 1);

            float aA=1.f, aB=0.f, rA_=1.f, rB_=0.f;
            if (lane < L) {                             // aggregate
                float4 s = Sarr[j];
                aA=s.x; aB=s.y; rA_=s.z; rB_=s.w;
            } else if (lane == L && jbase + L < nblk) { // inclusive terminator
                float4 s = Incl[jbase + L];
                aA=s.x; aB=s.y; rA_=s.z; rB_=s.w;
            }
            // suffix-compose lanes 0..63 (lanes > L are identity); lane 0 gets batch map
            #pragma unroll
            for (int st = 1; st < 64; st <<= 1) {
                float oAa = __shfl_down(aA,  st);
                float oBa = __shfl_down(aB,  st);
                float oAr = __shfl_down(rA_, st);
                float oBr = __shfl_down(rB_, st);
                if (lane + st < 64) {
                    post_compose(aA,  aB,  oAa, oBa);
                    post_compose(rA_, rB_, oAr, oBr);
                }
            }
            float bAa = __shfl(aA, 0),  bBa = __shfl(aB, 0);
            float bAr = __shfl(rA_, 0), bBr = __shfl(rB_, 0);
            post_compose(MAa, MBa, bAa, bBa);
            post_compose(MAr, MBr, bAr, bBr);

            if (L < 64) break;
            jbase += 64;
        }
        if (lane == 0) {
            s_cb[0] = MBa;                              // carry for advantages
            s_cb[1] = MBr;                              // carry for returns
            // publish inclusive: Incl_c = S_c ∘ M   (lane0 == tid0 holds S_c)
            float IAa = SAa, IBa = SBa, IAr = SAr, IBr = SBr;
            post_compose(IAa, IBa, MAa, MBa);
            post_compose(IAr, IBr, MAr, MBr);
            Incl[c] = make_float4(IAa, IBa, IAr, IBr);
            __hip_atomic_store(&flag[c], 2, __ATOMIC_RELEASE, __HIP_MEMORY_SCOPE_AGENT);
        }
    }
    __syncthreads();                                   // S2: carry ready
    const float cbA = s_cb[0];
    const float cbR = s_cb[1];

    // ---------------- Phase C: replay + store ----------------
    float xa = fmaf(WAa, cbA, WBa);   // value at this wave's right edge
    float xr = fmaf(WAr, cbR, WBr);
    xa = fmaf(eAa, xa, eBa);          // value at this thread's right edge
    xr = fmaf(eAr, xr, eBr);

    float ra[SEQ], rt[SEQ];
    #pragma unroll
    for (int i = SEQ - 1; i >= 0; --i) {
        bool val = (vbits >> i) & 1u;
        float a  = val ? GAMMA * TAU * fm[i] : 1.f;
        float cc = val ? GAMMA * fm[i]       : 1.f;
        xa = fmaf(a,  xa, delta[i]);
        xr = fmaf(cc, xr, dd[i]);
        ra[i] = xa; rt[i] = xr;
    }

    if (full) {
        #pragma unroll
        for (int q = 0; q < SEQ / 4; ++q) {
            ((float4*)(out_adv + base))[q] =
                make_float4(ra[4*q], ra[4*q+1], ra[4*q+2], ra[4*q+3]);
            ((float4*)(out_ret + base))[q] =
                make_float4(rt[4*q], rt[4*q+1], rt[4*q+2], rt[4*q+3]);
        }
    } else {
        #pragma unroll
        for (int i = 0; i < SEQ; ++i) {
            if (base + i < (long)T) {
                out_adv[base + i] = ra[i];
                out_ret[base + i] = rt[i];
            }
        }
    }
}

extern "C" void kernel_launch(void* const* d_in, const int* in_sizes, int n_in,
                              void* d_out, int out_size, void* d_ws, size_t ws_size,
                              hipStream_t stream) {
    const float* r  = (const float*)d_in[0];
    const float* v  = (const float*)d_in[1];
    const float* nv = (const float*)d_in[2];
    const int*   m  = (const int*)d_in[3];
    const int T = in_sizes[0];
    const int nblk = (T + CHUNK - 1) / CHUNK;   // 1024 for T = 4'194'304

    // ws layout: [ flags: nblk ints ][ Sarr: nblk float4 ][ Incl: nblk float4 ]
    int*    flag = (int*)d_ws;
    size_t  off  = ((size_t)nblk * sizeof(int) + 15) & ~(size_t)15;
    float4* Sarr = (float4*)((char*)d_ws + off);
    float4* Incl = Sarr + nblk;

    float* out_adv = (float*)d_out;
    float* out_ret = (float*)d_out + T;

    (void)hipMemsetAsync(flag, 0, (size_t)nblk * sizeof(int), stream);
    k_onepass<<<nblk, BLK, 0, stream>>>(r, v, nv, m, flag, Sarr, Incl,
                                        out_adv, out_ret, T, nblk);
}

// Round 7
// 112.822 us; speedup vs baseline: 1.1659x; 1.1265x over previous
//
#include <hip/hip_runtime.h>

#define GAMMA 0.99f
#define TAU   0.95f

constexpr int SEQ   = 16;          // elements per thread
constexpr int BLK   = 256;         // threads per block
constexpr int CHUNK = BLK * SEQ;   // 4096 elements per block

// (A,B) = (A,B) ∘ (rA,rB)  — apply right operand first, then (A,B)
__device__ __forceinline__ void post_compose(float& A, float& B, float rA, float rB) {
    B = fmaf(A, rB, B);
    A *= rA;
}
// (A,B) = (lA,lB) ∘ (A,B)  — apply (A,B) first, then left operand
__device__ __forceinline__ void pre_compose(float& A, float& B, float lA, float lB) {
    B = fmaf(lA, B, lB);
    A *= lA;
}

// =====================================================================
// Single-pass suffix scan, CUB-style decoupled lookback.
// Block b processes chunk c = nblk-1-b (reversed), so every chunk it
// depends on (c+1 .. nblk-1) belongs to an EARLIER-dispatched block ->
// with in-order workgroup dispatch no block waits on a later block.
// flag[j]: 0 = nothing, 1 = aggregate in Sarr[j], 2 = inclusive in Incl[j].
// Lookback walks predecessors in 64-wide batches; stops at first flag==2.
// Spin loads are RELAXED (an agent-scope acquire load invalidates the
// XCD L2 every poll -> chip-wide cache thrash, the round-6 pathology);
// one acquire FENCE per batch after the flags are observed provides the
// ordering for the Sarr/Incl reads.
// =====================================================================
__global__ __launch_bounds__(BLK) void k_onepass(
    const float* __restrict__ r, const float* __restrict__ v,
    const float* __restrict__ nv, const int* __restrict__ m,
    int* __restrict__ flag, float4* __restrict__ Sarr, float4* __restrict__ Incl,
    float* __restrict__ out_adv, float* __restrict__ out_ret, int T, int nblk)
{
    const int  tid  = threadIdx.x;
    const int  lane = tid & 63;
    const int  w    = tid >> 6;
    const int  c    = nblk - 1 - (int)blockIdx.x;   // chunk index (reversed)
    const long base = (long)c * CHUNK + (long)tid * SEQ;

    __shared__ float wSum[4][4];
    __shared__ float s_cb[2];

    // ---------------- Phase A: load chunk + per-element maps ----------------
    float fm[SEQ], delta[SEQ], dd[SEQ];
    unsigned vbits = 0;
    float Aa = 1.f, Ba = 0.f, Ar = 1.f, Br = 0.f;
    const bool full = (base + SEQ <= (long)T);

    if (full) {
        vbits = 0xFFFFu;
        float rr[SEQ], vv[SEQ + 1], nn[SEQ];
        #pragma unroll
        for (int q = 0; q < SEQ / 4; ++q) {
            float4 t0 = ((const float4*)(r  + base))[q];
            rr[4*q+0]=t0.x; rr[4*q+1]=t0.y; rr[4*q+2]=t0.z; rr[4*q+3]=t0.w;
            float4 t1 = ((const float4*)(v  + base))[q];
            vv[4*q+0]=t1.x; vv[4*q+1]=t1.y; vv[4*q+2]=t1.z; vv[4*q+3]=t1.w;
            float4 t2 = ((const float4*)(nv + base))[q];
            nn[4*q+0]=t2.x; nn[4*q+1]=t2.y; nn[4*q+2]=t2.z; nn[4*q+3]=t2.w;
            int4   t3 = ((const int4*)(m   + base))[q];
            fm[4*q+0]=(float)t3.x; fm[4*q+1]=(float)t3.y;
            fm[4*q+2]=(float)t3.z; fm[4*q+3]=(float)t3.w;
        }
        vv[SEQ] = (base + SEQ < (long)T) ? v[base + SEQ] : 0.f;
        #pragma unroll
        for (int i = SEQ - 1; i >= 0; --i) {
            delta[i] = rr[i] + GAMMA * fm[i] * vv[i+1] - vv[i];
            dd[i]    = rr[i] + GAMMA * (1.f - fm[i]) * nn[i];
            pre_compose(Aa, Ba, GAMMA * TAU * fm[i], delta[i]);
            pre_compose(Ar, Br, GAMMA * fm[i], dd[i]);
        }
    } else {
        #pragma unroll
        for (int ii = 0; ii < SEQ; ++ii) {
            int i = SEQ - 1 - ii;
            long idx = base + i;
            bool val = idx < (long)T;
            float rr  = val ? r[idx]  : 0.f;
            float vv0 = val ? v[idx]  : 0.f;
            float vv1 = (idx + 1 < (long)T) ? v[idx + 1] : 0.f;
            float nn  = val ? nv[idx] : 0.f;
            fm[i] = val ? (float)m[idx] : 0.f;
            if (val) vbits |= (1u << i);
            delta[i] = val ? (rr + GAMMA * fm[i] * vv1 - vv0) : 0.f;
            dd[i]    = val ? (rr + GAMMA * (1.f - fm[i]) * nn) : 0.f;
            pre_compose(Aa, Ba, val ? GAMMA * TAU * fm[i] : 1.f, delta[i]);
            pre_compose(Ar, Br, val ? GAMMA * fm[i] : 1.f, dd[i]);
        }
    }

    // wave-level inclusive suffix scan (contiguous segments, non-commutative OK)
    #pragma unroll
    for (int st = 1; st < 64; st <<= 1) {
        float oAa = __shfl_down(Aa, st);
        float oBa = __shfl_down(Ba, st);
        float oAr = __shfl_down(Ar, st);
        float oBr = __shfl_down(Br, st);
        if (lane + st < 64) {
            post_compose(Aa, Ba, oAa, oBa);
            post_compose(Ar, Br, oAr, oBr);
        }
    }
    // thread-exclusive (within wave)
    float eAa = __shfl_down(Aa, 1);
    float eBa = __shfl_down(Ba, 1);
    float eAr = __shfl_down(Ar, 1);
    float eBr = __shfl_down(Br, 1);
    if (lane == 63) { eAa=1.f; eBa=0.f; eAr=1.f; eBr=0.f; }

    if (lane == 0) { wSum[w][0]=Aa; wSum[w][1]=Ba; wSum[w][2]=Ar; wSum[w][3]=Br; }
    __syncthreads();                                   // S1: wSum ready

    // per-thread wave-exclusive map (waves w+1..3), kept in registers
    float WAa=1.f, WBa=0.f, WAr=1.f, WBr=0.f;
    for (int j = 3; j > w; --j) {
        pre_compose(WAa, WBa, wSum[j][0], wSum[j][1]);
        pre_compose(WAr, WBr, wSum[j][2], wSum[j][3]);
    }

    // tid0: block aggregate S_c -> publish (flag=1, release)
    float SAa=1.f, SBa=0.f, SAr=1.f, SBr=0.f;
    if (tid == 0) {
        for (int j = 3; j >= 0; --j) {
            pre_compose(SAa, SBa, wSum[j][0], wSum[j][1]);
            pre_compose(SAr, SBr, wSum[j][2], wSum[j][3]);
        }
        Sarr[c] = make_float4(SAa, SBa, SAr, SBr);
        __hip_atomic_store(&flag[c], 1, __ATOMIC_RELEASE, __HIP_MEMORY_SCOPE_AGENT);
    }

    // ---------------- Lookback (wave 0): M = S_{c+1} ∘ ... ∘ Incl_j ----------------
    if (w == 0) {
        float MAa=1.f, MBa=0.f, MAr=1.f, MBr=0.f;
        int jbase = c + 1;
        while (jbase < nblk) {
            int j = jbase + lane;
            int f = 2;                                  // beyond-end = inclusive identity
            if (j < nblk) {
                // RELAXED spin (no per-poll cache invalidate)
                f = __hip_atomic_load(&flag[j], __ATOMIC_RELAXED, __HIP_MEMORY_SCOPE_AGENT);
                while (f == 0) {
                    __builtin_amdgcn_s_sleep(4);
                    f = __hip_atomic_load(&flag[j], __ATOMIC_RELAXED, __HIP_MEMORY_SCOPE_AGENT);
                }
            }
            // one acquire fence per batch: orders Sarr/Incl reads after flags
            __builtin_amdgcn_fence(__ATOMIC_ACQUIRE, "agent");

            unsigned long long mask2 = __ballot(f == 2);
            int L = (mask2 == 0) ? 64 : (__ffsll((long long)mask2) - 1);

            float aA=1.f, aB=0.f, rA_=1.f, rB_=0.f;
            if (lane < L) {                             // aggregate
                float4 s = Sarr[j];
                aA=s.x; aB=s.y; rA_=s.z; rB_=s.w;
            } else if (lane == L && jbase + L < nblk) { // inclusive terminator
                float4 s = Incl[jbase + L];
                aA=s.x; aB=s.y; rA_=s.z; rB_=s.w;
            }
            // suffix-compose lanes 0..63 (lanes > L are identity); lane 0 gets batch map
            #pragma unroll
            for (int st = 1; st < 64; st <<= 1) {
                float oAa = __shfl_down(aA,  st);
                float oBa = __shfl_down(aB,  st);
                float oAr = __shfl_down(rA_, st);
                float oBr = __shfl_down(rB_, st);
                if (lane + st < 64) {
                    post_compose(aA,  aB,  oAa, oBa);
                    post_compose(rA_, rB_, oAr, oBr);
                }
            }
            float bAa = __shfl(aA, 0),  bBa = __shfl(aB, 0);
            float bAr = __shfl(rA_, 0), bBr = __shfl(rB_, 0);
            post_compose(MAa, MBa, bAa, bBa);
            post_compose(MAr, MBr, bAr, bBr);

            if (L < 64) break;
            jbase += 64;
        }
        if (lane == 0) {
            s_cb[0] = MBa;                              // carry for advantages
            s_cb[1] = MBr;                              // carry for returns
            // publish inclusive: Incl_c = S_c ∘ M   (lane0 == tid0 holds S_c)
            float IAa = SAa, IBa = SBa, IAr = SAr, IBr = SBr;
            post_compose(IAa, IBa, MAa, MBa);
            post_compose(IAr, IBr, MAr, MBr);
            Incl[c] = make_float4(IAa, IBa, IAr, IBr);
            __hip_atomic_store(&flag[c], 2, __ATOMIC_RELEASE, __HIP_MEMORY_SCOPE_AGENT);
        }
    }
    __syncthreads();                                   // S2: carry ready
    const float cbA = s_cb[0];
    const float cbR = s_cb[1];

    // ---------------- Phase C: replay + store ----------------
    float xa = fmaf(WAa, cbA, WBa);   // value at this wave's right edge
    float xr = fmaf(WAr, cbR, WBr);
    xa = fmaf(eAa, xa, eBa);          // value at this thread's right edge
    xr = fmaf(eAr, xr, eBr);

    float ra[SEQ], rt[SEQ];
    #pragma unroll
    for (int i = SEQ - 1; i >= 0; --i) {
        bool val = (vbits >> i) & 1u;
        float a  = val ? GAMMA * TAU * fm[i] : 1.f;
        float cc = val ? GAMMA * fm[i]       : 1.f;
        xa = fmaf(a,  xa, delta[i]);
        xr = fmaf(cc, xr, dd[i]);
        ra[i] = xa; rt[i] = xr;
    }

    if (full) {
        #pragma unroll
        for (int q = 0; q < SEQ / 4; ++q) {
            ((float4*)(out_adv + base))[q] =
                make_float4(ra[4*q], ra[4*q+1], ra[4*q+2], ra[4*q+3]);
            ((float4*)(out_ret + base))[q] =
                make_float4(rt[4*q], rt[4*q+1], rt[4*q+2], rt[4*q+3]);
        }
    } else {
        #pragma unroll
        for (int i = 0; i < SEQ; ++i) {
            if (base + i < (long)T) {
                out_adv[base + i] = ra[i];
                out_ret[base + i] = rt[i];
            }
        }
    }
}

extern "C" void kernel_launch(void* const* d_in, const int* in_sizes, int n_in,
                              void* d_out, int out_size, void* d_ws, size_t ws_size,
                              hipStream_t stream) {
    const float* r  = (const float*)d_in[0];
    const float* v  = (const float*)d_in[1];
    const float* nv = (const float*)d_in[2];
    const int*   m  = (const int*)d_in[3];
    const int T = in_sizes[0];
    const int nblk = (T + CHUNK - 1) / CHUNK;   // 1024 for T = 4'194'304

    // ws layout: [ flags: nblk ints ][ Sarr: nblk float4 ][ Incl: nblk float4 ]
    int*    flag = (int*)d_ws;
    size_t  off  = ((size_t)nblk * sizeof(int) + 15) & ~(size_t)15;
    float4* Sarr = (float4*)((char*)d_ws + off);
    float4* Incl = Sarr + nblk;

    float* out_adv = (float*)d_out;
    float* out_ret = (float*)d_out + T;

    (void)hipMemsetAsync(flag, 0, (size_t)nblk * sizeof(int), stream);
    k_onepass<<<nblk, BLK, 0, stream>>>(r, v, nv, m, flag, Sarr, Incl,
                                        out_adv, out_ret, T, nblk);
}

// Round 8
// 26.735 us; speedup vs baseline: 4.9200x; 4.2200x over previous
//
#include <hip/hip_runtime.h>

#define GAMMA 0.99f
#define TAU   0.95f

constexpr int SEQ   = 16;          // elements per thread
constexpr int BLK   = 256;         // threads per block
constexpr int CHUNK = BLK * SEQ;   // 4096 elements per block

// (A,B) = (A,B) ∘ (rA,rB)  — apply right operand first, then (A,B)
__device__ __forceinline__ void post_compose(float& A, float& B, float rA, float rB) {
    B = fmaf(A, rB, B);
    A *= rA;
}
// (A,B) = (lA,lB) ∘ (A,B)  — apply (A,B) first, then left operand
__device__ __forceinline__ void pre_compose(float& A, float& B, float lA, float lB) {
    B = fmaf(lA, B, lB);
    A *= lA;
}

// =====================================================================
// Single kernel, ZERO cross-block communication.
// Key fact: at m[i]==0 the recurrences reset (adv[i]=r[i]-v[i],
// ret[i]=r[i]+gamma*nv[i], both carry-independent). So each block
// derives its own exact carry (adv[p], ret[p]) for p = next chunk start
// by composing the per-element affine maps rightward from p until the
// first m==0 (or end of array) — the zero-mask map has A=0, so
// everything beyond it is annihilated: the composition is EXACT.
// With Bernoulli masks the walk terminates in the first 64-wide batch
// with probability 1 - 2^-64.
// =====================================================================
__global__ __launch_bounds__(BLK) void k_fused1(
    const float* __restrict__ r, const float* __restrict__ v,
    const float* __restrict__ nv, const int* __restrict__ m,
    float* __restrict__ out_adv, float* __restrict__ out_ret, int T)
{
    const int  tid  = threadIdx.x;
    const int  lane = tid & 63;
    const int  w    = tid >> 6;
    const int  c    = (int)blockIdx.x;
    const long base = (long)c * CHUNK + (long)tid * SEQ;

    __shared__ float wSum[4][4];
    __shared__ float s_cb[2];

    // ---------------- Phase A: load chunk + per-element maps ----------------
    float fm[SEQ], delta[SEQ], dd[SEQ];
    unsigned vbits = 0;
    float Aa = 1.f, Ba = 0.f, Ar = 1.f, Br = 0.f;
    const bool full = (base + SEQ <= (long)T);

    if (full) {
        vbits = 0xFFFFu;
        float rr[SEQ], vv[SEQ + 1], nn[SEQ];
        #pragma unroll
        for (int q = 0; q < SEQ / 4; ++q) {
            float4 t0 = ((const float4*)(r  + base))[q];
            rr[4*q+0]=t0.x; rr[4*q+1]=t0.y; rr[4*q+2]=t0.z; rr[4*q+3]=t0.w;
            float4 t1 = ((const float4*)(v  + base))[q];
            vv[4*q+0]=t1.x; vv[4*q+1]=t1.y; vv[4*q+2]=t1.z; vv[4*q+3]=t1.w;
            float4 t2 = ((const float4*)(nv + base))[q];
            nn[4*q+0]=t2.x; nn[4*q+1]=t2.y; nn[4*q+2]=t2.z; nn[4*q+3]=t2.w;
            int4   t3 = ((const int4*)(m   + base))[q];
            fm[4*q+0]=(float)t3.x; fm[4*q+1]=(float)t3.y;
            fm[4*q+2]=(float)t3.z; fm[4*q+3]=(float)t3.w;
        }
        vv[SEQ] = (base + SEQ < (long)T) ? v[base + SEQ] : 0.f;
        #pragma unroll
        for (int i = SEQ - 1; i >= 0; --i) {
            delta[i] = rr[i] + GAMMA * fm[i] * vv[i+1] - vv[i];
            dd[i]    = rr[i] + GAMMA * (1.f - fm[i]) * nn[i];
            pre_compose(Aa, Ba, GAMMA * TAU * fm[i], delta[i]);
            pre_compose(Ar, Br, GAMMA * fm[i], dd[i]);
        }
    } else {
        #pragma unroll
        for (int ii = 0; ii < SEQ; ++ii) {
            int i = SEQ - 1 - ii;
            long idx = base + i;
            bool val = idx < (long)T;
            float rr  = val ? r[idx]  : 0.f;
            float vv0 = val ? v[idx]  : 0.f;
            float vv1 = (idx + 1 < (long)T) ? v[idx + 1] : 0.f;
            float nn  = val ? nv[idx] : 0.f;
            fm[i] = val ? (float)m[idx] : 0.f;
            if (val) vbits |= (1u << i);
            delta[i] = val ? (rr + GAMMA * fm[i] * vv1 - vv0) : 0.f;
            dd[i]    = val ? (rr + GAMMA * (1.f - fm[i]) * nn) : 0.f;
            pre_compose(Aa, Ba, val ? GAMMA * TAU * fm[i] : 1.f, delta[i]);
            pre_compose(Ar, Br, val ? GAMMA * fm[i] : 1.f, dd[i]);
        }
    }

    // wave-level inclusive suffix scan (contiguous segments, non-commutative OK)
    #pragma unroll
    for (int st = 1; st < 64; st <<= 1) {
        float oAa = __shfl_down(Aa, st);
        float oBa = __shfl_down(Ba, st);
        float oAr = __shfl_down(Ar, st);
        float oBr = __shfl_down(Br, st);
        if (lane + st < 64) {
            post_compose(Aa, Ba, oAa, oBa);
            post_compose(Ar, Br, oAr, oBr);
        }
    }
    // thread-exclusive (within wave)
    float eAa = __shfl_down(Aa, 1);
    float eBa = __shfl_down(Ba, 1);
    float eAr = __shfl_down(Ar, 1);
    float eBr = __shfl_down(Br, 1);
    if (lane == 63) { eAa=1.f; eBa=0.f; eAr=1.f; eBr=0.f; }

    if (lane == 0) { wSum[w][0]=Aa; wSum[w][1]=Ba; wSum[w][2]=Ar; wSum[w][3]=Br; }
    __syncthreads();                                   // S1: wSum ready

    // per-thread wave-exclusive map (waves w+1..3), kept in registers
    float WAa=1.f, WBa=0.f, WAr=1.f, WBr=0.f;
    for (int j = 3; j > w; --j) {
        pre_compose(WAa, WBa, wSum[j][0], wSum[j][1]);
        pre_compose(WAr, WBr, wSum[j][2], wSum[j][3]);
    }

    // ---------------- Carry: wave 0 composes element maps from p until first m==0 ----------------
    if (w == 0) {
        const long p = (long)(c + 1) * CHUNK;          // next chunk start
        float MAa=1.f, MBa=0.f, MAr=1.f, MBr=0.f;
        if (p < (long)T) {
            long jb = p;
            while (true) {
                long i = jb + lane;
                bool have = i < (long)T;
                float aA=1.f, aB=0.f, rA_=1.f, rB_=0.f;
                float mi = 0.f;
                if (have) {
                    mi = (float)m[i];
                    float ri  = r[i];
                    float vi  = v[i];
                    float vi1 = (i + 1 < (long)T) ? v[i + 1] : 0.f;
                    float nvi = nv[i];
                    aA  = GAMMA * TAU * mi;
                    aB  = ri + GAMMA * mi * vi1 - vi;
                    rA_ = GAMMA * mi;
                    rB_ = ri + GAMMA * (1.f - mi) * nvi;
                }
                bool term = (!have) || (mi == 0.f);
                unsigned long long bz = __ballot(term);

                // suffix-compose the 64 element maps (lane gets [lane..63])
                #pragma unroll
                for (int st = 1; st < 64; st <<= 1) {
                    float oAa = __shfl_down(aA,  st);
                    float oBa = __shfl_down(aB,  st);
                    float oAr = __shfl_down(rA_, st);
                    float oBr = __shfl_down(rB_, st);
                    if (lane + st < 64) {
                        post_compose(aA,  aB,  oAa, oBa);
                        post_compose(rA_, rB_, oAr, oBr);
                    }
                }
                float bAa = __shfl(aA, 0),  bBa = __shfl(aB, 0);
                float bAr = __shfl(rA_, 0), bBr = __shfl(rB_, 0);
                post_compose(MAa, MBa, bAa, bBa);
                post_compose(MAr, MBr, bAr, bBr);

                if (bz != 0ull) break;   // this batch contains a reset (or array end)
                jb += 64;
            }
        }
        if (lane == 0) {
            s_cb[0] = MBa;   // adv[p]  (M applied to 0)
            s_cb[1] = MBr;   // ret[p]
        }
    }
    __syncthreads();                                   // S2: carry ready
    const float cbA = s_cb[0];
    const float cbR = s_cb[1];

    // ---------------- Phase C: replay + store ----------------
    float xa = fmaf(WAa, cbA, WBa);   // value at this wave's right edge
    float xr = fmaf(WAr, cbR, WBr);
    xa = fmaf(eAa, xa, eBa);          // value at this thread's right edge
    xr = fmaf(eAr, xr, eBr);

    float ra[SEQ], rt[SEQ];
    #pragma unroll
    for (int i = SEQ - 1; i >= 0; --i) {
        bool val = (vbits >> i) & 1u;
        float a  = val ? GAMMA * TAU * fm[i] : 1.f;
        float cc = val ? GAMMA * fm[i]       : 1.f;
        xa = fmaf(a,  xa, delta[i]);
        xr = fmaf(cc, xr, dd[i]);
        ra[i] = xa; rt[i] = xr;
    }

    if (full) {
        #pragma unroll
        for (int q = 0; q < SEQ / 4; ++q) {
            ((float4*)(out_adv + base))[q] =
                make_float4(ra[4*q], ra[4*q+1], ra[4*q+2], ra[4*q+3]);
            ((float4*)(out_ret + base))[q] =
                make_float4(rt[4*q], rt[4*q+1], rt[4*q+2], rt[4*q+3]);
        }
    } else {
        #pragma unroll
        for (int i = 0; i < SEQ; ++i) {
            if (base + i < (long)T) {
                out_adv[base + i] = ra[i];
                out_ret[base + i] = rt[i];
            }
        }
    }
}

extern "C" void kernel_launch(void* const* d_in, const int* in_sizes, int n_in,
                              void* d_out, int out_size, void* d_ws, size_t ws_size,
                              hipStream_t stream) {
    const float* r  = (const float*)d_in[0];
    const float* v  = (const float*)d_in[1];
    const float* nv = (const float*)d_in[2];
    const int*   m  = (const int*)d_in[3];
    const int T = in_sizes[0];
    const int nblk = (T + CHUNK - 1) / CHUNK;   // 1024 for T = 4'194'304

    float* out_adv = (float*)d_out;
    float* out_ret = (float*)d_out + T;

    k_fused1<<<nblk, BLK, 0, stream>>>(r, v, nv, m, out_adv, out_ret, T);
}

// Round 9
// 26.171 us; speedup vs baseline: 5.0261x; 1.0216x over previous
//
#include <hip/hip_runtime.h>

#define GAMMA 0.99f
#define TAU   0.95f
#define GTAU  (GAMMA * TAU)

constexpr int SEQ   = 16;          // elements per thread
constexpr int BLK   = 256;         // threads per block
constexpr int CHUNK = BLK * SEQ;   // 4096 elements per block

// (A,B) = (A,B) ∘ (rA,rB)  — apply right operand first, then (A,B)
__device__ __forceinline__ void post_compose(float& A, float& B, float rA, float rB) {
    B = fmaf(A, rB, B);
    A *= rA;
}
// (A,B) = (lA,lB) ∘ (A,B)  — apply (A,B) first, then left operand
__device__ __forceinline__ void pre_compose(float& A, float& B, float lA, float lB) {
    B = fmaf(lA, B, lB);
    A *= lA;
}

// =====================================================================
// Single kernel, zero cross-block communication (round-8 design) with:
//  - __launch_bounds__(256,4): 128-VGPR budget -> no scratch spill of the
//    per-element arrays (round 6/7 showed VGPR=56 + ~14MB excess WRITE_SIZE)
//  - mask bits instead of fm[] array (saves 16 VGPRs)
//  - stores fused into the replay loop (saves 32 VGPRs)
//  - carry-window prefetch issued before phase A (hides the dependent
//    memory round-trip under the main chunk load)
// Carry: at m[i]==0 both recurrences reset (maps with A=0 annihilate all
// later terms), so composing element maps from p rightward to the first
// m==0 (or end) gives the EXACT carry. Bernoulli masks -> first 64-wide
// batch suffices with prob 1-2^-64; loop continues otherwise (correct for
// any data).
// =====================================================================
__global__ __launch_bounds__(BLK, 4) void k_fused1(
    const float* __restrict__ r, const float* __restrict__ v,
    const float* __restrict__ nv, const int* __restrict__ m,
    float* __restrict__ out_adv, float* __restrict__ out_ret, int T)
{
    const int  tid  = threadIdx.x;
    const int  lane = tid & 63;
    const int  w    = tid >> 6;
    const int  c    = (int)blockIdx.x;
    const long base = (long)c * CHUNK + (long)tid * SEQ;
    const long p    = (long)(c + 1) * CHUNK;        // next chunk start

    __shared__ float wSum[4][4];
    __shared__ float s_cb[2];

    // ---- carry-window prefetch (wave 0): issue loads BEFORE phase A ----
    float pm = 0.f, pr = 0.f, pv = 0.f, pv1 = 0.f, pnv = 0.f;
    if (w == 0 && p < (long)T) {
        long i = p + lane;
        if (i < (long)T) {
            pm  = (float)m[i];
            pr  = r[i];
            pv  = v[i];
            pv1 = (i + 1 < (long)T) ? v[i + 1] : 0.f;
            pnv = nv[i];
        }
    }

    // ---------------- Phase A: load chunk + per-element maps ----------------
    float delta[SEQ], dd[SEQ];
    unsigned vbits = 0, mbits = 0;
    float Aa = 1.f, Ba = 0.f, Ar = 1.f, Br = 0.f;
    const bool full = (base + SEQ <= (long)T);

    if (full) {
        vbits = 0xFFFFu;
        float rr[SEQ], vv[SEQ + 1], nn[SEQ], fmv[SEQ];
        #pragma unroll
        for (int q = 0; q < SEQ / 4; ++q) {
            float4 t0 = ((const float4*)(r  + base))[q];
            rr[4*q+0]=t0.x; rr[4*q+1]=t0.y; rr[4*q+2]=t0.z; rr[4*q+3]=t0.w;
            float4 t1 = ((const float4*)(v  + base))[q];
            vv[4*q+0]=t1.x; vv[4*q+1]=t1.y; vv[4*q+2]=t1.z; vv[4*q+3]=t1.w;
            float4 t2 = ((const float4*)(nv + base))[q];
            nn[4*q+0]=t2.x; nn[4*q+1]=t2.y; nn[4*q+2]=t2.z; nn[4*q+3]=t2.w;
            int4   t3 = ((const int4*)(m   + base))[q];
            fmv[4*q+0]=(float)t3.x; fmv[4*q+1]=(float)t3.y;
            fmv[4*q+2]=(float)t3.z; fmv[4*q+3]=(float)t3.w;
        }
        vv[SEQ] = (base + SEQ < (long)T) ? v[base + SEQ] : 0.f;
        #pragma unroll
        for (int i = SEQ - 1; i >= 0; --i) {
            if (fmv[i] != 0.f) mbits |= (1u << i);
            delta[i] = rr[i] + GAMMA * fmv[i] * vv[i+1] - vv[i];
            dd[i]    = rr[i] + GAMMA * (1.f - fmv[i]) * nn[i];
            pre_compose(Aa, Ba, GTAU * fmv[i], delta[i]);
            pre_compose(Ar, Br, GAMMA * fmv[i], dd[i]);
        }
    } else {
        #pragma unroll
        for (int ii = 0; ii < SEQ; ++ii) {
            int i = SEQ - 1 - ii;
            long idx = base + i;
            bool val = idx < (long)T;
            float rr  = val ? r[idx]  : 0.f;
            float vv0 = val ? v[idx]  : 0.f;
            float vv1 = (idx + 1 < (long)T) ? v[idx + 1] : 0.f;
            float nn  = val ? nv[idx] : 0.f;
            float fmv = val ? (float)m[idx] : 0.f;
            if (val) vbits |= (1u << i);
            if (val && fmv != 0.f) mbits |= (1u << i);
            delta[i] = val ? (rr + GAMMA * fmv * vv1 - vv0) : 0.f;
            dd[i]    = val ? (rr + GAMMA * (1.f - fmv) * nn) : 0.f;
            pre_compose(Aa, Ba, val ? GTAU * fmv : 1.f, delta[i]);
            pre_compose(Ar, Br, val ? GAMMA * fmv : 1.f, dd[i]);
        }
    }

    // wave-level inclusive suffix scan (contiguous segments, non-commutative OK)
    #pragma unroll
    for (int st = 1; st < 64; st <<= 1) {
        float oAa = __shfl_down(Aa, st);
        float oBa = __shfl_down(Ba, st);
        float oAr = __shfl_down(Ar, st);
        float oBr = __shfl_down(Br, st);
        if (lane + st < 64) {
            post_compose(Aa, Ba, oAa, oBa);
            post_compose(Ar, Br, oAr, oBr);
        }
    }
    // thread-exclusive (within wave)
    float eAa = __shfl_down(Aa, 1);
    float eBa = __shfl_down(Ba, 1);
    float eAr = __shfl_down(Ar, 1);
    float eBr = __shfl_down(Br, 1);
    if (lane == 63) { eAa=1.f; eBa=0.f; eAr=1.f; eBr=0.f; }

    if (lane == 0) { wSum[w][0]=Aa; wSum[w][1]=Ba; wSum[w][2]=Ar; wSum[w][3]=Br; }
    __syncthreads();                                   // S1: wSum ready

    // per-thread wave-exclusive map (waves w+1..3)
    float WAa=1.f, WBa=0.f, WAr=1.f, WBr=0.f;
    for (int j = 3; j > w; --j) {
        pre_compose(WAa, WBa, wSum[j][0], wSum[j][1]);
        pre_compose(WAr, WBr, wSum[j][2], wSum[j][3]);
    }

    // ---- Carry: wave 0 composes element maps from p to first m==0 ----
    if (w == 0) {
        float MAa=1.f, MBa=0.f, MAr=1.f, MBr=0.f;
        if (p < (long)T) {
            // ---- first batch: prefetched ----
            {
                long i = p + lane;
                bool have = i < (long)T;
                float aA=1.f, aB=0.f, rA_=1.f, rB_=0.f;
                if (have) {
                    aA  = GTAU * pm;
                    aB  = pr + GAMMA * pm * pv1 - pv;
                    rA_ = GAMMA * pm;
                    rB_ = pr + GAMMA * (1.f - pm) * pnv;
                }
                bool term = (!have) || (pm == 0.f);
                unsigned long long bz = __ballot(term);
                #pragma unroll
                for (int st = 1; st < 64; st <<= 1) {
                    float oAa = __shfl_down(aA,  st);
                    float oBa = __shfl_down(aB,  st);
                    float oAr = __shfl_down(rA_, st);
                    float oBr = __shfl_down(rB_, st);
                    if (lane + st < 64) {
                        post_compose(aA,  aB,  oAa, oBa);
                        post_compose(rA_, rB_, oAr, oBr);
                    }
                }
                MAa = __shfl(aA, 0);  MBa = __shfl(aB, 0);
                MAr = __shfl(rA_, 0); MBr = __shfl(rB_, 0);
                if (bz != 0ull) goto carry_done;
            }
            // ---- rare: continue past the first 64 elements ----
            for (long jb = p + 64; ; jb += 64) {
                long i = jb + lane;
                bool have = i < (long)T;
                float aA=1.f, aB=0.f, rA_=1.f, rB_=0.f;
                float mi = 0.f;
                if (have) {
                    mi = (float)m[i];
                    float ri  = r[i];
                    float vi  = v[i];
                    float vi1 = (i + 1 < (long)T) ? v[i + 1] : 0.f;
                    float nvi = nv[i];
                    aA  = GTAU * mi;
                    aB  = ri + GAMMA * mi * vi1 - vi;
                    rA_ = GAMMA * mi;
                    rB_ = ri + GAMMA * (1.f - mi) * nvi;
                }
                bool term = (!have) || (mi == 0.f);
                unsigned long long bz = __ballot(term);
                #pragma unroll
                for (int st = 1; st < 64; st <<= 1) {
                    float oAa = __shfl_down(aA,  st);
                    float oBa = __shfl_down(aB,  st);
                    float oAr = __shfl_down(rA_, st);
                    float oBr = __shfl_down(rB_, st);
                    if (lane + st < 64) {
                        post_compose(aA,  aB,  oAa, oBa);
                        post_compose(rA_, rB_, oAr, oBr);
                    }
                }
                float bAa = __shfl(aA, 0),  bBa = __shfl(aB, 0);
                float bAr = __shfl(rA_, 0), bBr = __shfl(rB_, 0);
                post_compose(MAa, MBa, bAa, bBa);
                post_compose(MAr, MBr, bAr, bBr);
                if (bz != 0ull) break;
            }
        }
carry_done:
        if (lane == 0) {
            s_cb[0] = MBa;   // adv[p]  (M applied to 0)
            s_cb[1] = MBr;   // ret[p]
        }
    }
    __syncthreads();                                   // S2: carry ready
    const float cbA = s_cb[0];
    const float cbR = s_cb[1];

    // ---------------- Phase C: replay + store (fused) ----------------
    float xa = fmaf(WAa, cbA, WBa);   // value at this wave's right edge
    float xr = fmaf(WAr, cbR, WBr);
    xa = fmaf(eAa, xa, eBa);          // value at this thread's right edge
    xr = fmaf(eAr, xr, eBr);

    if (full) {
        #pragma unroll
        for (int q = SEQ / 4 - 1; q >= 0; --q) {
            float ta[4], tr[4];
            #pragma unroll
            for (int k = 3; k >= 0; --k) {
                int i = 4 * q + k;
                float a  = (mbits >> i & 1u) ? GTAU  : 0.f;
                float cc = (mbits >> i & 1u) ? GAMMA : 0.f;
                xa = fmaf(a,  xa, delta[i]);
                xr = fmaf(cc, xr, dd[i]);
                ta[k] = xa; tr[k] = xr;
            }
            ((float4*)(out_adv + base))[q] = make_float4(ta[0], ta[1], ta[2], ta[3]);
            ((float4*)(out_ret + base))[q] = make_float4(tr[0], tr[1], tr[2], tr[3]);
        }
    } else {
        #pragma unroll
        for (int i = SEQ - 1; i >= 0; --i) {
            bool val = (vbits >> i) & 1u;
            float a  = val ? ((mbits >> i & 1u) ? GTAU  : 0.f) : 1.f;
            float cc = val ? ((mbits >> i & 1u) ? GAMMA : 0.f) : 1.f;
            xa = fmaf(a,  xa, delta[i]);
            xr = fmaf(cc, xr, dd[i]);
            if (base + i < (long)T) {
                out_adv[base + i] = xa;
                out_ret[base + i] = xr;
            }
        }
    }
}

extern "C" void kernel_launch(void* const* d_in, const int* in_sizes, int n_in,
                              void* d_out, int out_size, void* d_ws, size_t ws_size,
                              hipStream_t stream) {
    const float* r  = (const float*)d_in[0];
    const float* v  = (const float*)d_in[1];
    const float* nv = (const float*)d_in[2];
    const int*   m  = (const int*)d_in[3];
    const int T = in_sizes[0];
    const int nblk = (T + CHUNK - 1) / CHUNK;   // 1024 for T = 4'194'304

    float* out_adv = (float*)d_out;
    float* out_ret = (float*)d_out + T;

    k_fused1<<<nblk, BLK, 0, stream>>>(r, v, nv, m, out_adv, out_ret, T);
}

// Round 10
// 24.226 us; speedup vs baseline: 5.4295x; 1.0803x over previous
//
#include <hip/hip_runtime.h>

#define GAMMA 0.99f
#define TAU   0.95f
#define GTAU  (GAMMA * TAU)

constexpr int SEQ   = 4;           // elements per thread (one float4)
constexpr int BLK   = 256;         // threads per block
constexpr int CHUNK = BLK * SEQ;   // 1024 elements per block

// (A,B) = (A,B) ∘ (rA,rB)  — apply right operand first, then (A,B)
__device__ __forceinline__ void post_compose(float& A, float& B, float rA, float rB) {
    B = fmaf(A, rB, B);
    A *= rA;
}
// (A,B) = (lA,lB) ∘ (A,B)  — apply (A,B) first, then left operand
__device__ __forceinline__ void pre_compose(float& A, float& B, float lA, float lB) {
    B = fmaf(lA, B, lB);
    A *= lA;
}

// =====================================================================
// Single kernel, zero cross-block communication (round-8 design), with
// SEQ=4 so every global access is perfectly coalesced: lane i's float4
// sits at base + i*16B -> one wave load instruction = 1KB contiguous
// (SEQ=16 blocked layout had 64 lanes touching 64 distinct cachelines
// per instruction = 4x request amplification, the round-8/9 limiter).
// v[i+1] boundary value comes from __shfl_down instead of a per-thread
// scalar load (lane 63 only does the scalar load).
// Carry: at m[i]==0 both recurrences reset (map A=0 annihilates later
// terms), so composing element maps rightward from p to the first m==0
// (or array end) is the EXACT carry. Bernoulli masks -> terminates in
// the first 64-wide batch with prob 1-2^-64; loops further otherwise.
// =====================================================================
__global__ __launch_bounds__(BLK) void k_fused1(
    const float* __restrict__ r, const float* __restrict__ v,
    const float* __restrict__ nv, const int* __restrict__ m,
    float* __restrict__ out_adv, float* __restrict__ out_ret, int T)
{
    const int  tid  = threadIdx.x;
    const int  lane = tid & 63;
    const int  w    = tid >> 6;
    const int  c    = (int)blockIdx.x;
    const long base = (long)c * CHUNK + (long)tid * SEQ;
    const long p    = (long)(c + 1) * CHUNK;        // next chunk start

    __shared__ float wSum[4][4];
    __shared__ float s_cb[2];

    // ---- carry-window prefetch (wave 0): issue loads BEFORE phase A ----
    float pm = 0.f, pr = 0.f, pv = 0.f, pv1 = 0.f, pnv = 0.f;
    if (w == 0 && p < (long)T) {
        long i = p + lane;
        if (i < (long)T) {
            pm  = (float)m[i];
            pr  = r[i];
            pv  = v[i];
            pv1 = (i + 1 < (long)T) ? v[i + 1] : 0.f;
            pnv = nv[i];
        }
    }

    // ---------------- Phase A: load chunk + per-element maps ----------------
    float delta[SEQ], dd[SEQ];
    unsigned vbits = 0, mbits = 0;
    float Aa = 1.f, Ba = 0.f, Ar = 1.f, Br = 0.f;

    // wave-uniform: whole 256-element wave segment in range?
    const bool wfull = ((long)c * CHUNK + (long)(w + 1) * 64 * SEQ) <= (long)T;

    if (wfull) {
        vbits = 0xFu;
        float4 r4 = *(const float4*)(r  + base);
        float4 v4 = *(const float4*)(v  + base);
        float4 n4 = *(const float4*)(nv + base);
        int4   m4 = *(const int4*)  (m  + base);
        float vnext = __shfl_down(v4.x, 1);            // lane+1's v[base]
        if (lane == 63) vnext = (base + SEQ < (long)T) ? v[base + SEQ] : 0.f;

        float rr[4]  = {r4.x, r4.y, r4.z, r4.w};
        float vv[5]  = {v4.x, v4.y, v4.z, v4.w, vnext};
        float nn[4]  = {n4.x, n4.y, n4.z, n4.w};
        float fmv[4] = {(float)m4.x, (float)m4.y, (float)m4.z, (float)m4.w};
        #pragma unroll
        for (int i = SEQ - 1; i >= 0; --i) {
            if (fmv[i] != 0.f) mbits |= (1u << i);
            delta[i] = rr[i] + GAMMA * fmv[i] * vv[i+1] - vv[i];
            dd[i]    = rr[i] + GAMMA * (1.f - fmv[i]) * nn[i];
            pre_compose(Aa, Ba, GTAU  * fmv[i], delta[i]);
            pre_compose(Ar, Br, GAMMA * fmv[i], dd[i]);
        }
    } else {
        #pragma unroll
        for (int ii = 0; ii < SEQ; ++ii) {
            int i = SEQ - 1 - ii;
            long idx = base + i;
            bool val = idx < (long)T;
            float rr  = val ? r[idx]  : 0.f;
            float vv0 = val ? v[idx]  : 0.f;
            float vv1 = (idx + 1 < (long)T) ? v[idx + 1] : 0.f;
            float nn  = val ? nv[idx] : 0.f;
            float fmv = val ? (float)m[idx] : 0.f;
            if (val) vbits |= (1u << i);
            if (val && fmv != 0.f) mbits |= (1u << i);
            delta[i] = val ? (rr + GAMMA * fmv * vv1 - vv0) : 0.f;
            dd[i]    = val ? (rr + GAMMA * (1.f - fmv) * nn) : 0.f;
            pre_compose(Aa, Ba, val ? GTAU * fmv  : 1.f, delta[i]);
            pre_compose(Ar, Br, val ? GAMMA * fmv : 1.f, dd[i]);
        }
    }

    // wave-level inclusive suffix scan (contiguous segments, non-commutative OK)
    #pragma unroll
    for (int st = 1; st < 64; st <<= 1) {
        float oAa = __shfl_down(Aa, st);
        float oBa = __shfl_down(Ba, st);
        float oAr = __shfl_down(Ar, st);
        float oBr = __shfl_down(Br, st);
        if (lane + st < 64) {
            post_compose(Aa, Ba, oAa, oBa);
            post_compose(Ar, Br, oAr, oBr);
        }
    }
    // thread-exclusive (within wave)
    float eAa = __shfl_down(Aa, 1);
    float eBa = __shfl_down(Ba, 1);
    float eAr = __shfl_down(Ar, 1);
    float eBr = __shfl_down(Br, 1);
    if (lane == 63) { eAa=1.f; eBa=0.f; eAr=1.f; eBr=0.f; }

    if (lane == 0) { wSum[w][0]=Aa; wSum[w][1]=Ba; wSum[w][2]=Ar; wSum[w][3]=Br; }
    __syncthreads();                                   // S1: wSum ready

    // per-thread wave-exclusive map (waves w+1..3)
    float WAa=1.f, WBa=0.f, WAr=1.f, WBr=0.f;
    for (int j = 3; j > w; --j) {
        pre_compose(WAa, WBa, wSum[j][0], wSum[j][1]);
        pre_compose(WAr, WBr, wSum[j][2], wSum[j][3]);
    }

    // ---- Carry: wave 0 composes element maps from p to first m==0 ----
    if (w == 0) {
        float MAa=1.f, MBa=0.f, MAr=1.f, MBr=0.f;
        if (p < (long)T) {
            // ---- first batch: prefetched ----
            {
                long i = p + lane;
                bool have = i < (long)T;
                float aA=1.f, aB=0.f, rA_=1.f, rB_=0.f;
                if (have) {
                    aA  = GTAU * pm;
                    aB  = pr + GAMMA * pm * pv1 - pv;
                    rA_ = GAMMA * pm;
                    rB_ = pr + GAMMA * (1.f - pm) * pnv;
                }
                bool term = (!have) || (pm == 0.f);
                unsigned long long bz = __ballot(term);
                #pragma unroll
                for (int st = 1; st < 64; st <<= 1) {
                    float oAa = __shfl_down(aA,  st);
                    float oBa = __shfl_down(aB,  st);
                    float oAr = __shfl_down(rA_, st);
                    float oBr = __shfl_down(rB_, st);
                    if (lane + st < 64) {
                        post_compose(aA,  aB,  oAa, oBa);
                        post_compose(rA_, rB_, oAr, oBr);
                    }
                }
                MAa = __shfl(aA, 0);  MBa = __shfl(aB, 0);
                MAr = __shfl(rA_, 0); MBr = __shfl(rB_, 0);
                if (bz != 0ull) goto carry_done;
            }
            // ---- rare: continue past the first 64 elements ----
            for (long jb = p + 64; ; jb += 64) {
                long i = jb + lane;
                bool have = i < (long)T;
                float aA=1.f, aB=0.f, rA_=1.f, rB_=0.f;
                float mi = 0.f;
                if (have) {
                    mi = (float)m[i];
                    float ri  = r[i];
                    float vi  = v[i];
                    float vi1 = (i + 1 < (long)T) ? v[i + 1] : 0.f;
                    float nvi = nv[i];
                    aA  = GTAU * mi;
                    aB  = ri + GAMMA * mi * vi1 - vi;
                    rA_ = GAMMA * mi;
                    rB_ = ri + GAMMA * (1.f - mi) * nvi;
                }
                bool term = (!have) || (mi == 0.f);
                unsigned long long bz = __ballot(term);
                #pragma unroll
                for (int st = 1; st < 64; st <<= 1) {
                    float oAa = __shfl_down(aA,  st);
                    float oBa = __shfl_down(aB,  st);
                    float oAr = __shfl_down(rA_, st);
                    float oBr = __shfl_down(rB_, st);
                    if (lane + st < 64) {
                        post_compose(aA,  aB,  oAa, oBa);
                        post_compose(rA_, rB_, oAr, oBr);
                    }
                }
                float bAa = __shfl(aA, 0),  bBa = __shfl(aB, 0);
                float bAr = __shfl(rA_, 0), bBr = __shfl(rB_, 0);
                post_compose(MAa, MBa, bAa, bBa);
                post_compose(MAr, MBr, bAr, bBr);
                if (bz != 0ull) break;
            }
        }
carry_done:
        if (lane == 0) {
            s_cb[0] = MBa;   // adv[p]  (M applied to 0)
            s_cb[1] = MBr;   // ret[p]
        }
    }
    __syncthreads();                                   // S2: carry ready
    const float cbA = s_cb[0];
    const float cbR = s_cb[1];

    // ---------------- Phase C: replay + store (coalesced float4) ----------------
    float xa = fmaf(WAa, cbA, WBa);   // value at this wave's right edge
    float xr = fmaf(WAr, cbR, WBr);
    xa = fmaf(eAa, xa, eBa);          // value at this thread's right edge
    xr = fmaf(eAr, xr, eBr);

    if (wfull) {
        float ta[4], tr[4];
        #pragma unroll
        for (int i = SEQ - 1; i >= 0; --i) {
            float a  = (mbits >> i & 1u) ? GTAU  : 0.f;
            float cc = (mbits >> i & 1u) ? GAMMA : 0.f;
            xa = fmaf(a,  xa, delta[i]);
            xr = fmaf(cc, xr, dd[i]);
            ta[i] = xa; tr[i] = xr;
        }
        *(float4*)(out_adv + base) = make_float4(ta[0], ta[1], ta[2], ta[3]);
        *(float4*)(out_ret + base) = make_float4(tr[0], tr[1], tr[2], tr[3]);
    } else {
        #pragma unroll
        for (int i = SEQ - 1; i >= 0; --i) {
            bool val = (vbits >> i) & 1u;
            float a  = val ? ((mbits >> i & 1u) ? GTAU  : 0.f) : 1.f;
            float cc = val ? ((mbits >> i & 1u) ? GAMMA : 0.f) : 1.f;
            xa = fmaf(a,  xa, delta[i]);
            xr = fmaf(cc, xr, dd[i]);
            if (base + i < (long)T) {
                out_adv[base + i] = xa;
                out_ret[base + i] = xr;
            }
        }
    }
}

extern "C" void kernel_launch(void* const* d_in, const int* in_sizes, int n_in,
                              void* d_out, int out_size, void* d_ws, size_t ws_size,
                              hipStream_t stream) {
    const float* r  = (const float*)d_in[0];
    const float* v  = (const float*)d_in[1];
    const float* nv = (const float*)d_in[2];
    const int*   m  = (const int*)d_in[3];
    const int T = in_sizes[0];
    const int nblk = (T + CHUNK - 1) / CHUNK;   // 4096 for T = 4'194'304

    float* out_adv = (float*)d_out;
    float* out_ret = (float*)d_out + T;

    k_fused1<<<nblk, BLK, 0, stream>>>(r, v, nv, m, out_adv, out_ret, T);
}

// Round 11
// 22.823 us; speedup vs baseline: 5.7633x; 1.0615x over previous
//
#include <hip/hip_runtime.h>

#define GAMMA 0.99f
#define TAU   0.95f
#define GTAU  (GAMMA * TAU)

constexpr int WSEQ   = 4;            // elements per lane (one float4)
constexpr int WCHUNK = 64 * WSEQ;    // 256 elements per wave
constexpr int BLK    = 256;          // 4 independent waves per block

// (A,B) = (A,B) ∘ (rA,rB)  — apply right operand first, then (A,B)
__device__ __forceinline__ void post_compose(float& A, float& B, float rA, float rB) {
    B = fmaf(A, rB, B);
    A *= rA;
}
// (A,B) = (lA,lB) ∘ (A,B)  — apply (A,B) first, then left operand
__device__ __forceinline__ void pre_compose(float& A, float& B, float lA, float lB) {
    B = fmaf(lA, B, lB);
    A *= lA;
}

// =====================================================================
// Fully wave-independent GAE scan: each wave owns a 256-element chunk.
// No __syncthreads, no LDS, no cross-block (or cross-wave) communication.
//  - lane i loads one float4 per stream at base + i*16B: perfectly
//    coalesced (1KB/wave-instruction).
//  - carry: at m[i]==0 both recurrences reset (map A=0 annihilates all
//    later terms), so composing element maps rightward from p (next
//    chunk start) to the first m==0 or array end gives the EXACT carry.
//    All 64 lanes cooperate; Bernoulli masks terminate in the first
//    64-wide batch with prob 1-2^-64 (loop continues otherwise).
//  - lane 63's v[base+4] boundary == v[p] == lane 0's window value ->
//    one __shfl instead of a scalar load.
// =====================================================================
__global__ __launch_bounds__(BLK) void k_wave(
    const float* __restrict__ r, const float* __restrict__ v,
    const float* __restrict__ nv, const int* __restrict__ m,
    float* __restrict__ out_adv, float* __restrict__ out_ret, int T, int nchunk)
{
    const int  lane  = threadIdx.x & 63;
    const int  w     = threadIdx.x >> 6;
    const int  chunk = (int)blockIdx.x * 4 + w;
    if (chunk >= nchunk) return;                      // wave-uniform exit

    const long base = (long)chunk * WCHUNK + (long)lane * WSEQ;
    const long p    = (long)(chunk + 1) * WCHUNK;     // next chunk start

    // ---- carry-window prefetch: issue early, all 64 lanes ----
    float pm = 0.f, pr = 0.f, pv = 0.f, pv1 = 0.f, pnv = 0.f;
    if (p < (long)T) {
        long i = p + lane;
        if (i < (long)T) {
            pm  = (float)m[i];
            pr  = r[i];
            pv  = v[i];
            pv1 = (i + 1 < (long)T) ? v[i + 1] : 0.f;
            pnv = nv[i];
        }
    }

    // ---------------- Phase A: load chunk + per-element maps ----------------
    float delta[WSEQ], dd[WSEQ];
    unsigned vbits = 0, mbits = 0;
    float Aa = 1.f, Ba = 0.f, Ar = 1.f, Br = 0.f;
    const bool full = (p <= (long)T);                 // whole chunk in range

    if (full) {
        vbits = 0xFu;
        float4 r4 = *(const float4*)(r  + base);
        float4 v4 = *(const float4*)(v  + base);
        float4 n4 = *(const float4*)(nv + base);
        int4   m4 = *(const int4*)  (m  + base);
        float vhi   = __shfl(pv, 0);                  // v[p] (0 if p>=T)
        float vnext = __shfl_down(v4.x, 1);           // lane+1's v[base]
        if (lane == 63) vnext = vhi;

        float rr[4]  = {r4.x, r4.y, r4.z, r4.w};
        float vv[5]  = {v4.x, v4.y, v4.z, v4.w, vnext};
        float nn[4]  = {n4.x, n4.y, n4.z, n4.w};
        float fmv[4] = {(float)m4.x, (float)m4.y, (float)m4.z, (float)m4.w};
        #pragma unroll
        for (int i = WSEQ - 1; i >= 0; --i) {
            if (fmv[i] != 0.f) mbits |= (1u << i);
            delta[i] = rr[i] + GAMMA * fmv[i] * vv[i+1] - vv[i];
            dd[i]    = rr[i] + GAMMA * (1.f - fmv[i]) * nn[i];
            pre_compose(Aa, Ba, GTAU  * fmv[i], delta[i]);
            pre_compose(Ar, Br, GAMMA * fmv[i], dd[i]);
        }
    } else {
        #pragma unroll
        for (int ii = 0; ii < WSEQ; ++ii) {
            int i = WSEQ - 1 - ii;
            long idx = base + i;
            bool val = idx < (long)T;
            float rr  = val ? r[idx]  : 0.f;
            float vv0 = val ? v[idx]  : 0.f;
            float vv1 = (idx + 1 < (long)T) ? v[idx + 1] : 0.f;
            float nn  = val ? nv[idx] : 0.f;
            float fmv = val ? (float)m[idx] : 0.f;
            if (val) vbits |= (1u << i);
            if (val && fmv != 0.f) mbits |= (1u << i);
            delta[i] = val ? (rr + GAMMA * fmv * vv1 - vv0) : 0.f;
            dd[i]    = val ? (rr + GAMMA * (1.f - fmv) * nn) : 0.f;
            pre_compose(Aa, Ba, val ? GTAU * fmv  : 1.f, delta[i]);
            pre_compose(Ar, Br, val ? GAMMA * fmv : 1.f, dd[i]);
        }
    }

    // wave-level inclusive suffix scan (contiguous segments, non-commutative OK)
    #pragma unroll
    for (int st = 1; st < 64; st <<= 1) {
        float oAa = __shfl_down(Aa, st);
        float oBa = __shfl_down(Ba, st);
        float oAr = __shfl_down(Ar, st);
        float oBr = __shfl_down(Br, st);
        if (lane + st < 64) {
            post_compose(Aa, Ba, oAa, oBa);
            post_compose(Ar, Br, oAr, oBr);
        }
    }
    // thread-exclusive (within wave)
    float eAa = __shfl_down(Aa, 1);
    float eBa = __shfl_down(Ba, 1);
    float eAr = __shfl_down(Ar, 1);
    float eBr = __shfl_down(Br, 1);
    if (lane == 63) { eAa=1.f; eBa=0.f; eAr=1.f; eBr=0.f; }

    // ---- Carry: compose element maps from p to first m==0 (all lanes) ----
    float cbA = 0.f, cbR = 0.f;
    if (p < (long)T) {
        float MAa, MBa, MAr, MBr;
        // first batch: prefetched
        {
            long i = p + lane;
            bool have = i < (long)T;
            float aA=1.f, aB=0.f, rA_=1.f, rB_=0.f;
            if (have) {
                aA  = GTAU * pm;
                aB  = pr + GAMMA * pm * pv1 - pv;
                rA_ = GAMMA * pm;
                rB_ = pr + GAMMA * (1.f - pm) * pnv;
            }
            bool term = (!have) || (pm == 0.f);
            unsigned long long bz = __ballot(term);
            #pragma unroll
            for (int st = 1; st < 64; st <<= 1) {
                float oAa = __shfl_down(aA,  st);
                float oBa = __shfl_down(aB,  st);
                float oAr = __shfl_down(rA_, st);
                float oBr = __shfl_down(rB_, st);
                if (lane + st < 64) {
                    post_compose(aA,  aB,  oAa, oBa);
                    post_compose(rA_, rB_, oAr, oBr);
                }
            }
            MAa = __shfl(aA, 0);  MBa = __shfl(aB, 0);
            MAr = __shfl(rA_, 0); MBr = __shfl(rB_, 0);
            if (bz == 0ull) {
                // rare: continue past the first 64 elements
                for (long jb = p + 64; ; jb += 64) {
                    long i2 = jb + lane;
                    bool have2 = i2 < (long)T;
                    float aA2=1.f, aB2=0.f, rA2=1.f, rB2=0.f;
                    float mi = 0.f;
                    if (have2) {
                        mi = (float)m[i2];
                        float ri  = r[i2];
                        float vi  = v[i2];
                        float vi1 = (i2 + 1 < (long)T) ? v[i2 + 1] : 0.f;
                        float nvi = nv[i2];
                        aA2 = GTAU * mi;
                        aB2 = ri + GAMMA * mi * vi1 - vi;
                        rA2 = GAMMA * mi;
                        rB2 = ri + GAMMA * (1.f - mi) * nvi;
                    }
                    bool term2 = (!have2) || (mi == 0.f);
                    unsigned long long bz2 = __ballot(term2);
                    #pragma unroll
                    for (int st = 1; st < 64; st <<= 1) {
                        float oAa = __shfl_down(aA2, st);
                        float oBa = __shfl_down(aB2, st);
                        float oAr = __shfl_down(rA2, st);
                        float oBr = __shfl_down(rB2, st);
                        if (lane + st < 64) {
                            post_compose(aA2, aB2, oAa, oBa);
                            post_compose(rA2, rB2, oAr, oBr);
                        }
                    }
                    float bAa = __shfl(aA2, 0), bBa = __shfl(aB2, 0);
                    float bAr = __shfl(rA2, 0), bBr = __shfl(rB2, 0);
                    post_compose(MAa, MBa, bAa, bBa);
                    post_compose(MAr, MBr, bAr, bBr);
                    if (bz2 != 0ull) break;
                }
            }
        }
        cbA = MBa;   // adv[p]  (M applied to 0)
        cbR = MBr;   // ret[p]
    }

    // ---------------- Phase C: replay + store (coalesced float4) ----------------
    float xa = fmaf(eAa, cbA, eBa);   // value at this thread's right edge
    float xr = fmaf(eAr, cbR, eBr);

    if (full) {
        float ta[4], tr[4];
        #pragma unroll
        for (int i = WSEQ - 1; i >= 0; --i) {
            float a  = (mbits >> i & 1u) ? GTAU  : 0.f;
            float cc = (mbits >> i & 1u) ? GAMMA : 0.f;
            xa = fmaf(a,  xa, delta[i]);
            xr = fmaf(cc, xr, dd[i]);
            ta[i] = xa; tr[i] = xr;
        }
        *(float4*)(out_adv + base) = make_float4(ta[0], ta[1], ta[2], ta[3]);
        *(float4*)(out_ret + base) = make_float4(tr[0], tr[1], tr[2], tr[3]);
    } else {
        #pragma unroll
        for (int i = WSEQ - 1; i >= 0; --i) {
            bool val = (vbits >> i) & 1u;
            float a  = val ? ((mbits >> i & 1u) ? GTAU  : 0.f) : 1.f;
            float cc = val ? ((mbits >> i & 1u) ? GAMMA : 0.f) : 1.f;
            xa = fmaf(a,  xa, delta[i]);
            xr = fmaf(cc, xr, dd[i]);
            if (base + i < (long)T) {
                out_adv[base + i] = xa;
                out_ret[base + i] = xr;
            }
        }
    }
}

extern "C" void kernel_launch(void* const* d_in, const int* in_sizes, int n_in,
                              void* d_out, int out_size, void* d_ws, size_t ws_size,
                              hipStream_t stream) {
    const float* r  = (const float*)d_in[0];
    const float* v  = (const float*)d_in[1];
    const float* nv = (const float*)d_in[2];
    const int*   m  = (const int*)d_in[3];
    const int T = in_sizes[0];
    const int nchunk = (T + WCHUNK - 1) / WCHUNK;   // 16384 for T = 2^22
    const int nblk   = (nchunk + 3) / 4;

    float* out_adv = (float*)d_out;
    float* out_ret = (float*)d_out + T;

    k_wave<<<nblk, BLK, 0, stream>>>(r, v, nv, m, out_adv, out_ret, T, nchunk);
}